// Round 1
// baseline (47.665 us; speedup 1.0000x reference)
//
#include <hip/hip_runtime.h>

// Problem geometry (fixed by reference): B=16, L=2048, D=1024, fp32.
constexpr int L_CONST = 2048;
constexpr int D_CONST = 1024;
constexpr int SCAN_T  = 256;               // threads in build_order block
constexpr int PER     = L_CONST / SCAN_T;  // 8 positions per thread

// Kernel A: per batch row, compute the stable-partition permutation.
// order[b*L + dest] = src, where dest is src's position after putting all
// nl!=0 positions first (stable) followed by nl==0 positions (stable).
__global__ __launch_bounds__(SCAN_T) void build_order_kernel(
    const int* __restrict__ nl, int* __restrict__ order) {
    const int b = blockIdx.x;
    const int t = threadIdx.x;
    const int* row = nl + (size_t)b * L_CONST;

    int flags[PER];
    int cnt = 0;
    #pragma unroll
    for (int k = 0; k < PER; ++k) {
        int v = row[t * PER + k];
        flags[k] = (v != 0) ? 1 : 0;
        cnt += flags[k];
    }

    // Block-wide inclusive scan (Hillis-Steele) of per-thread nonpad counts.
    __shared__ int s[SCAN_T];
    s[t] = cnt;
    __syncthreads();
    #pragma unroll
    for (int off = 1; off < SCAN_T; off <<= 1) {
        int add = (t >= off) ? s[t - off] : 0;
        __syncthreads();
        s[t] += add;
        __syncthreads();
    }
    const int incl     = s[t];
    const int totalNon = s[SCAN_T - 1];
    const int exclNon  = incl - cnt;   // nonpads strictly before this thread's span

    int run = 0;
    #pragma unroll
    for (int k = 0; k < PER; ++k) {
        const int j        = t * PER + k;       // source position
        const int npPrefix = exclNon + run;     // nonpads strictly before j
        int dest;
        if (flags[k]) dest = npPrefix;                       // fact: stable front
        else          dest = totalNon + (j - npPrefix);      // pad: stable back
        order[(size_t)b * L_CONST + dest] = j;
        run += flags[k];
    }
}

// Kernel B: permuted row copy. One block per output row; each thread moves
// one float4 (D=1024 floats = 256 float4). Fully coalesced on both sides.
__global__ __launch_bounds__(256) void gather_kernel(
    const float* __restrict__ in, const int* __restrict__ order,
    float* __restrict__ out) {
    constexpr int D4 = D_CONST / 4;      // 256
    const int bi  = blockIdx.x;          // b*L + i (dest row)
    const int b   = bi >> 11;            // /L
    const int src = order[bi];           // block-uniform -> scalar broadcast
    const float4* srcp = (const float4*)in  + ((size_t)b * L_CONST + src) * D4;
    float4*       dstp = (float4*)out       + (size_t)bi * D4;
    dstp[threadIdx.x] = srcp[threadIdx.x];
}

extern "C" void kernel_launch(void* const* d_in, const int* in_sizes, int n_in,
                              void* d_out, int out_size, void* d_ws, size_t ws_size,
                              hipStream_t stream) {
    const float* sentout = (const float*)d_in[0];
    const int*   nl      = (const int*)d_in[1];
    float*       out     = (float*)d_out;
    int*         order   = (int*)d_ws;       // B*L ints = 128 KiB scratch

    const int B = in_sizes[1] / L_CONST;     // 16

    build_order_kernel<<<B, SCAN_T, 0, stream>>>(nl, order);
    gather_kernel<<<B * L_CONST, 256, 0, stream>>>(sentout, order, out);
}

// Round 2
// 47.267 us; speedup vs baseline: 1.0084x; 1.0084x over previous
//
#include <hip/hip_runtime.h>

// Problem geometry (fixed by reference): B=16, L=2048, D=1024, fp32.
constexpr int L_CONST = 2048;
constexpr int D_CONST = 1024;
constexpr int NT      = 256;              // threads per block
constexpr int PER     = L_CONST / NT;     // 8 flags per thread
constexpr int ROWS    = 16;               // dest rows copied per block
constexpr int GROUPS  = L_CONST / ROWS;   // 128 blocks per batch row
constexpr int D4      = D_CONST / 4;      // 256 float4 per row

// Fused kernel: each block recomputes the stable-partition permutation for
// its batch row (flags are L2-resident: B*L*4 = 128 KB total), inverts it
// into LDS (dest -> src), then copies its ROWS dest rows with one
// float4/lane/row. Single launch: no inter-kernel serialization.
__global__ __launch_bounds__(NT) void fused_partition_gather(
    const float* __restrict__ in, const int* __restrict__ nl,
    float* __restrict__ out) {
    const int b = blockIdx.x / GROUPS;    // batch row
    const int g = blockIdx.x % GROUPS;    // dest-row group within batch row
    const int t = threadIdx.x;

    // --- Phase 1: per-row stable-partition scan (src -> dest), invert in LDS.
    const int4* row4 = (const int4*)(nl + (size_t)b * L_CONST);
    int4 v0 = row4[t * 2];
    int4 v1 = row4[t * 2 + 1];
    int flags[PER];
    flags[0] = (v0.x != 0); flags[1] = (v0.y != 0);
    flags[2] = (v0.z != 0); flags[3] = (v0.w != 0);
    flags[4] = (v1.x != 0); flags[5] = (v1.y != 0);
    flags[6] = (v1.z != 0); flags[7] = (v1.w != 0);
    int cnt = 0;
    #pragma unroll
    for (int k = 0; k < PER; ++k) cnt += flags[k];

    __shared__ int s[NT];
    __shared__ int lds_order[L_CONST];    // dest -> src, 8 KB
    s[t] = cnt;
    __syncthreads();
    #pragma unroll
    for (int off = 1; off < NT; off <<= 1) {
        int add = (t >= off) ? s[t - off] : 0;
        __syncthreads();
        s[t] += add;
        __syncthreads();
    }
    const int incl     = s[t];
    const int totalNon = s[NT - 1];
    const int exclNon  = incl - cnt;      // nonpads strictly before this span

    int run = 0;
    #pragma unroll
    for (int k = 0; k < PER; ++k) {
        const int j        = t * PER + k;            // source position
        const int npPrefix = exclNon + run;          // nonpads strictly before j
        const int dest = flags[k] ? npPrefix : (totalNon + (j - npPrefix));
        lds_order[dest] = j;                         // all dests distinct: no race
        run += flags[k];
    }
    __syncthreads();

    // --- Phase 2: copy ROWS dest rows; src index is a broadcast LDS read.
    int srcs[ROWS];
    #pragma unroll
    for (int r = 0; r < ROWS; ++r) srcs[r] = lds_order[g * ROWS + r];

    const float4* inb  = (const float4*)in  + (size_t)b * L_CONST * D4;
    float4*       outb = (float4*)out       + ((size_t)b * L_CONST + (size_t)g * ROWS) * D4;
    #pragma unroll
    for (int r = 0; r < ROWS; ++r) {
        outb[r * D4 + t] = inb[(size_t)srcs[r] * D4 + t];
    }
}

extern "C" void kernel_launch(void* const* d_in, const int* in_sizes, int n_in,
                              void* d_out, int out_size, void* d_ws, size_t ws_size,
                              hipStream_t stream) {
    const float* sentout = (const float*)d_in[0];
    const int*   nl      = (const int*)d_in[1];
    float*       out     = (float*)d_out;

    const int B = in_sizes[1] / L_CONST;  // 16
    fused_partition_gather<<<B * GROUPS, NT, 0, stream>>>(sentout, nl, out);
}

// Round 4
// 45.396 us; speedup vs baseline: 1.0500x; 1.0412x over previous
//
#include <hip/hip_runtime.h>

// Problem geometry (fixed by reference): B=16, L=2048, D=1024, fp32.
constexpr int L_CONST = 2048;
constexpr int D_CONST = 1024;
constexpr int NT      = 256;              // threads per block
constexpr int PER     = L_CONST / NT;     // 8 flags per thread
constexpr int ROWS    = 16;               // dest rows copied per block
constexpr int GROUPS  = L_CONST / ROWS;   // 128 blocks per batch row
constexpr int D4      = D_CONST / 4;      // 256 float4 per row

// Native clang vector (NOT HIP_vector_type) so __builtin_nontemporal_* accepts it.
typedef float floatx4 __attribute__((ext_vector_type(4)));

// Fused kernel: each block recomputes the stable-partition permutation for
// its batch row (flags L2-resident: 128 KB total), inverts it into LDS
// (dest -> src), then copies its ROWS dest rows with one float4/lane/row.
// Stores are NON-TEMPORAL: output is write-once/read-never, so keeping it
// out of L2/L3 preserves the input's L3 residency across graph replays
// (R2 counters: regular stores evicted half the input -> 66 MB re-fetch).
__global__ __launch_bounds__(NT) void fused_partition_gather(
    const float* __restrict__ in, const int* __restrict__ nl,
    float* __restrict__ out) {
    const int b = blockIdx.x / GROUPS;    // batch row
    const int g = blockIdx.x % GROUPS;    // dest-row group within batch row
    const int t = threadIdx.x;

    // --- Phase 1: per-row stable-partition scan (src -> dest), invert in LDS.
    const int4* row4 = (const int4*)(nl + (size_t)b * L_CONST);
    int4 v0 = row4[t * 2];
    int4 v1 = row4[t * 2 + 1];
    int flags[PER];
    flags[0] = (v0.x != 0); flags[1] = (v0.y != 0);
    flags[2] = (v0.z != 0); flags[3] = (v0.w != 0);
    flags[4] = (v1.x != 0); flags[5] = (v1.y != 0);
    flags[6] = (v1.z != 0); flags[7] = (v1.w != 0);
    int cnt = 0;
    #pragma unroll
    for (int k = 0; k < PER; ++k) cnt += flags[k];

    __shared__ int s[NT];
    __shared__ int lds_order[L_CONST];    // dest -> src, 8 KB
    s[t] = cnt;
    __syncthreads();
    #pragma unroll
    for (int off = 1; off < NT; off <<= 1) {
        int add = (t >= off) ? s[t - off] : 0;
        __syncthreads();
        s[t] += add;
        __syncthreads();
    }
    const int incl     = s[t];
    const int totalNon = s[NT - 1];
    const int exclNon  = incl - cnt;      // nonpads strictly before this span

    int run = 0;
    #pragma unroll
    for (int k = 0; k < PER; ++k) {
        const int j        = t * PER + k;            // source position
        const int npPrefix = exclNon + run;          // nonpads strictly before j
        const int dest = flags[k] ? npPrefix : (totalNon + (j - npPrefix));
        lds_order[dest] = j;                         // all dests distinct: no race
        run += flags[k];
    }
    __syncthreads();

    // --- Phase 2: copy ROWS dest rows; src index is a broadcast LDS read.
    int srcs[ROWS];
    #pragma unroll
    for (int r = 0; r < ROWS; ++r) srcs[r] = lds_order[g * ROWS + r];

    const floatx4* inb  = (const floatx4*)in + (size_t)b * L_CONST * D4;
    floatx4*       outb = (floatx4*)out      + ((size_t)b * L_CONST + (size_t)g * ROWS) * D4;
    #pragma unroll
    for (int r = 0; r < ROWS; ++r) {
        floatx4 v = inb[(size_t)srcs[r] * D4 + t];
        __builtin_nontemporal_store(v, &outb[r * D4 + t]);
    }
}

extern "C" void kernel_launch(void* const* d_in, const int* in_sizes, int n_in,
                              void* d_out, int out_size, void* d_ws, size_t ws_size,
                              hipStream_t stream) {
    const float* sentout = (const float*)d_in[0];
    const int*   nl      = (const int*)d_in[1];
    float*       out     = (float*)d_out;

    const int B = in_sizes[1] / L_CONST;  // 16
    fused_partition_gather<<<B * GROUPS, NT, 0, stream>>>(sentout, nl, out);
}